// Round 6
// baseline (153.327 us; speedup 1.0000x reference)
//
#include <hip/hip_runtime.h>

#define N 8192
#define D 256
#define INV_TAU 14.285714285714286f
#define SCALE2 20.60992915555662f    // INV_TAU * log2(e)
#define LN2F 0.6931471805599453f
#define EPSN 1e-6f
#define MAXM 64                      // class-size cap (Poisson(8); P(>40) ~ 1e-16)

// fused-lse geometry: 128 rows/block (4 waves x 32 rows), 32 column splits
#define RT 128
#define CT 64             // cols per LDS tile
#define CSPLIT 32
#define CPB (N / CSPLIT)  // 256 cols per block
#define NTILES (CPB / CT) // 4 tiles

typedef unsigned int u32x4 __attribute__((ext_vector_type(4)));
typedef __bf16 bf16x8 __attribute__((ext_vector_type(8)));
typedef float f32x4 __attribute__((ext_vector_type(4)));

__device__ inline unsigned short f2bf(float x) {
    unsigned int u = __builtin_bit_cast(unsigned int, x);
    u += 0x7fffu + ((u >> 16) & 1u);   // RNE (finite inputs)
    return (unsigned short)(u >> 16);
}
__device__ inline float b2f(unsigned short u) {
    unsigned int x = (unsigned int)u << 16;
    return __builtin_bit_cast(float, x);
}
__device__ inline float fexp2(float x) {
#if __has_builtin(__builtin_amdgcn_exp2f)
    return __builtin_amdgcn_exp2f(x);
#else
    return __expf(x * 0.6931471805599453f);
#endif
}

// One wave per row: normalize -> bf16. A rows are pre-scaled by SCALE2 so the
// GEMM epilogue is exp2(dot) with no multiply. Bm is 16B-chunk XOR-swizzled
// (chunk c of row r stored at c ^ (r&7)) so LDS fragment reads are
// conflict-free while global->LDS staging stays a linear copy. Also builds
// per-class member lists (cnt zeroed by the preceding memset) and zeroes the
// output accumulator.
__global__ void ntx_prep(const float* __restrict__ im, const float* __restrict__ rec,
                         const int* __restrict__ labels,
                         unsigned short* __restrict__ A, unsigned short* __restrict__ Bm,
                         float* __restrict__ diag, float* __restrict__ rowsum,
                         int* __restrict__ cnt, unsigned short* __restrict__ members,
                         float* __restrict__ out) {
    const int wave = threadIdx.x >> 6;
    const int lane = threadIdx.x & 63;
    const int row  = blockIdx.x * 4 + wave;

    const float4 a = ((const float4*)(im  + (size_t)row * D))[lane];
    const float4 b = ((const float4*)(rec + (size_t)row * D))[lane];

    float ssa = a.x*a.x + a.y*a.y + a.z*a.z + a.w*a.w;
    float ssb = b.x*b.x + b.y*b.y + b.z*b.z + b.w*b.w;
    float dt  = a.x*b.x + a.y*b.y + a.z*b.z + a.w*b.w;
    #pragma unroll
    for (int o = 32; o; o >>= 1) {
        ssa += __shfl_xor(ssa, o);
        ssb += __shfl_xor(ssb, o);
        dt  += __shfl_xor(dt , o);
    }
    const float ra = SCALE2 / fmaxf(sqrtf(ssa), EPSN);   // scaled into A
    const float rb = 1.0f   / fmaxf(sqrtf(ssb), EPSN);

    ushort4 pa, pb;
    pa.x = f2bf(a.x*ra); pa.y = f2bf(a.y*ra); pa.z = f2bf(a.z*ra); pa.w = f2bf(a.w*ra);
    pb.x = f2bf(b.x*rb); pb.y = f2bf(b.y*rb); pb.z = f2bf(b.z*rb); pb.w = f2bf(b.w*rb);

    *(ushort4*)(A + (size_t)row * D + lane * 4) = pa;
    const int chunk = lane >> 1;
    const int sw = chunk ^ (row & 7);
    *(ushort4*)(Bm + (size_t)row * D + sw * 8 + (lane & 1) * 4) = pb;

    if (lane == 0) {
        diag[row]   = (dt / SCALE2) * ra * rb * INV_TAU;  // fp32 i2r[i,i], unscaled
        rowsum[row] = 0.0f;                               // ws is poisoned each launch
        const int lab = labels[row];
        const int u = atomicAdd(&cnt[lab], 1);
        if (u < MAXM) members[lab * MAXM + u] = (unsigned short)row;
        if (row == 0) out[0] = 0.0f;                      // d_out is poisoned too
    }
}

// Fused GEMM + UNMASKED sum-of-exp2 per row. 2048 blocks x 256 threads.
// Single 32 KB LDS buffer -> 4 blocks/CU resident (16 waves/CU): cross-block
// stagger covers barrier drains and keeps the matrix pipe fed.
__global__ __launch_bounds__(256, 4)
void ntx_lse(const unsigned short* __restrict__ A, const unsigned short* __restrict__ Bm,
             float* __restrict__ rowsum) {
    __shared__ __align__(16) unsigned short Bs[CT][D];   // 32 KB, physically swizzled

    const int wave = threadIdx.x >> 6;
    const int lane = threadIdx.x & 63;
    const int g    = lane >> 4;
    const int n16  = lane & 15;

    const int rowblk = blockIdx.x & (N / RT - 1);   // 0..63
    const int colblk = blockIdx.x >> 6;             // 0..31 (row-major: L2 shares B slab)
    const int row0 = rowblk * RT + wave * 32;       // this wave's 32 rows
    const int col0 = colblk * CPB;

    // A fragments: 32 rows x K=256 in registers (64 VGPRs)
    bf16x8 afrag[2][8];
    #pragma unroll
    for (int rs = 0; rs < 2; ++rs) {
        const int r = row0 + rs * 16 + n16;
        #pragma unroll
        for (int k = 0; k < 8; ++k)
            afrag[rs][k] = __builtin_bit_cast(
                bf16x8, *(const u32x4*)(A + (size_t)r * D + k * 32 + g * 8));
    }

    float acc[2][4] = {{0.f,0.f,0.f,0.f},{0.f,0.f,0.f,0.f}};

    const char* gbase = (const char*)(Bm + (size_t)col0 * D);

    for (int t = 0; t < NTILES; ++t) {
        // stage tile t (32 KB linear copy, 1 KB per instr, direct to LDS)
        {
            const char* gsrc = gbase + t * (CT * D * 2);
            char* lbase = (char*)&Bs[0][0];
            #pragma unroll
            for (int i = 0; i < 8; ++i) {
                const int off = (i * 4 + wave) * 1024;
                __builtin_amdgcn_global_load_lds(
                    (const __attribute__((address_space(1))) void*)(gsrc + off + lane * 16),
                    (__attribute__((address_space(3))) void*)(lbase + off),
                    16, 0, 0);
            }
        }
        __syncthreads();   // drains the stage (vmcnt 0 at barrier)

        #pragma unroll
        for (int cs = 0; cs < 4; ++cs) {
            const int bc = cs * 16 + n16;
            bf16x8 bfrag[8];
            #pragma unroll
            for (int k = 0; k < 8; ++k)
                bfrag[k] = __builtin_bit_cast(
                    bf16x8, *(const u32x4*)(&Bs[bc][((k * 4 + g) ^ (bc & 7)) * 8]));

            #pragma unroll
            for (int rs = 0; rs < 2; ++rs) {
                f32x4 c = {0.f, 0.f, 0.f, 0.f};
                #pragma unroll
                for (int k = 0; k < 8; ++k)
                    c = __builtin_amdgcn_mfma_f32_16x16x32_bf16(
                            afrag[rs][k], bfrag[k], c, 0, 0, 0);
                #pragma unroll
                for (int q = 0; q < 4; ++q)
                    acc[rs][q] += fexp2(c[q]);   // A pre-scaled: no mul, no mask
            }
        }
        __syncthreads();   // all waves done reading before next tile overwrites
    }

    #pragma unroll
    for (int rs = 0; rs < 2; ++rs)
        #pragma unroll
        for (int q = 0; q < 4; ++q) {
            float v = acc[rs][q];
            v += __shfl_xor(v, 1);
            v += __shfl_xor(v, 2);
            v += __shfl_xor(v, 4);
            v += __shfl_xor(v, 8);
            if (n16 == 0)
                atomicAdd(&rowsum[row0 + rs * 16 + g * 4 + q], v);
        }
}

// One wave per 4 rows: subtract same-label off-diagonal exps, form the per-row
// loss ln(rowsum - corr) - diag, block-reduce, one atomicAdd(out, sum/N).
// 512 blocks -> 512 total same-address atomics (negligible tail).
__global__ void ntx_corr(const unsigned short* __restrict__ A,
                         const unsigned short* __restrict__ Bm,
                         const int* __restrict__ labels, const int* __restrict__ cnt,
                         const unsigned short* __restrict__ members,
                         const float* __restrict__ diag,
                         const float* __restrict__ rowsum,
                         float* __restrict__ out) {
    __shared__ float wred[4];
    const int wave = threadIdx.x >> 6;
    const int lane = threadIdx.x & 63;
    const int w = blockIdx.x * 4 + wave;   // 0..2047
    const int chunk = lane >> 1;

    float lsum = 0.f;
    for (int rr = 0; rr < 4; ++rr) {
        const int r = w * 4 + rr;
        const int lab = labels[r];
        const int m = min(cnt[lab], MAXM);

        const ushort4 av = *(const ushort4*)(A + (size_t)r * D + lane * 4);
        const float a0 = b2f(av.x), a1 = b2f(av.y), a2 = b2f(av.z), a3 = b2f(av.w);

        float sum = 0.f;
        for (int t = 0; t < m; ++t) {
            const int j = members[lab * MAXM + t];
            if (j == r) continue;
            const int sw = chunk ^ (j & 7);   // unswizzle Bm row j
            const ushort4 bv = *(const ushort4*)(Bm + (size_t)j * D + sw * 8 + (lane & 1) * 4);
            float d = a0 * b2f(bv.x) + a1 * b2f(bv.y) + a2 * b2f(bv.z) + a3 * b2f(bv.w);
            #pragma unroll
            for (int o = 32; o; o >>= 1) d += __shfl_xor(d, o);
            sum += fexp2(d);                  // A pre-scaled
        }
        lsum += log2f(rowsum[r] - sum) * LN2F - diag[r];
    }
    if (lane == 0) wred[wave] = lsum;
    __syncthreads();
    if (threadIdx.x == 0)
        atomicAdd(out, (wred[0] + wred[1] + wred[2] + wred[3]) * (1.0f / (float)N));
}

extern "C" void kernel_launch(void* const* d_in, const int* in_sizes, int n_in,
                              void* d_out, int out_size, void* d_ws, size_t ws_size,
                              hipStream_t stream) {
    const float* im     = (const float*)d_in[0];
    const float* rec    = (const float*)d_in[1];
    const int*   labels = (const int*)d_in[2];
    float* out = (float*)d_out;

    unsigned short* A  = (unsigned short*)d_ws;            // 4 MB bf16 im_n * SCALE2
    unsigned short* Bm = A + (size_t)N * D;                // 4 MB bf16 rec_n (swizzled)
    float* diag   = (float*)(Bm + (size_t)N * D);          // 32 KB
    float* rowsum = diag + N;                              // 32 KB
    int* cnt      = (int*)(rowsum + N);                    // 4 KB
    unsigned short* members = (unsigned short*)(cnt + 1024); // 128 KB

    hipMemsetAsync(cnt, 0, 1024 * sizeof(int), stream);
    ntx_prep<<<N / 4, 256, 0, stream>>>(im, rec, labels, A, Bm, diag, rowsum, cnt, members, out);
    ntx_lse<<<(N / RT) * CSPLIT, 256, 0, stream>>>(A, Bm, rowsum);
    ntx_corr<<<N / 16, 256, 0, stream>>>(A, Bm, labels, cnt, members, diag, rowsum, out);
}